// Round 2
// baseline (1023.990 us; speedup 1.0000x reference)
//
#include <hip/hip_runtime.h>
#include <hip/hip_bf16.h>
#include <math.h>

// Problem constants (match reference)
#define B_   2
#define T_   2048
#define TOK_ 512
#define POS_ 512
#define H_   16
#define D_   64
#define KVH_ 4

typedef float f32x4 __attribute__((ext_vector_type(4)));

// ---------------------------------------------------------------------------
// Generic fp32 tiled GEMM: C[M,N] = A[M,K] @ W[K,N]
//   A row i at: A + i*lda + aoff   (lets us slice x_pos / x_tok out of x)
//   W row-major K x N (leading dim Nld)
// MODE 0: plain write, C row-major with ld = Nld (used for out = attO @ Wo)
// MODE 1: Q projection -> apply per-head phase rotation, write (B,H,T,D)
// MODE 2: K/V projection -> write (B,KVH,T,D)
// Block: 256 threads (16x16), per-thread micro-tile = RMxRN quadrants of 4x4
// where RM=BM/64, RN=BN/64. LDS strides padded +4 floats: keeps every f32x4
// LDS access 16B-aligned and compute-phase reads at <=2-way bank conflict.
// ---------------------------------------------------------------------------
template<int BM, int BN, int MODE>
__global__ __launch_bounds__(256, 2)
void gemm_k(const float* __restrict__ A, int lda, int aoff,
            const float* __restrict__ W, int Ktot, int Nld,
            float* __restrict__ Cout, const float* __restrict__ angles)
{
    constexpr int RM = BM / 64;
    constexpr int RN = BN / 64;
    constexpr int SA = BM + 4;
    constexpr int SB = BN + 4;
    __shared__ float As[16 * SA];   // transposed: As[k][m]
    __shared__ float Bs[16 * SB];   // Bs[k][n]

    const int tid = threadIdx.x;
    const int tx  = tid & 15;
    const int ty  = tid >> 4;
    const int m0  = blockIdx.y * BM;
    const int n0  = blockIdx.x * BN;

    float acc[RM][RN][4][4] = {};

    for (int k0 = 0; k0 < Ktot; k0 += 16) {
        __syncthreads();
        // A tile: BM x 16 -> As[k][m] (transposed scatter)
        #pragma unroll
        for (int it = 0; it < BM / 64; ++it) {
            int idx = tid + it * 256;          // 0 .. BM*4-1
            int row = idx >> 2;
            int k4  = (idx & 3) << 2;
            f32x4 av = *reinterpret_cast<const f32x4*>(
                A + (size_t)(m0 + row) * lda + aoff + k0 + k4);
            #pragma unroll
            for (int u = 0; u < 4; ++u) As[(k4 + u) * SA + row] = av[u];
        }
        // B tile: 16 x BN
        #pragma unroll
        for (int it = 0; it < BN / 64; ++it) {
            int idx = tid + it * 256;          // 0 .. BN*4-1
            int kr  = idx / (BN / 4);
            int c4  = (idx % (BN / 4)) << 2;
            *reinterpret_cast<f32x4*>(&Bs[kr * SB + c4]) =
                *reinterpret_cast<const f32x4*>(
                    W + (size_t)(k0 + kr) * Nld + n0 + c4);
        }
        __syncthreads();

        #pragma unroll
        for (int k = 0; k < 16; ++k) {
            f32x4 a[RM], b[RN];
            #pragma unroll
            for (int qm = 0; qm < RM; ++qm)
                a[qm] = *reinterpret_cast<const f32x4*>(&As[k * SA + qm * 64 + ty * 4]);
            #pragma unroll
            for (int qn = 0; qn < RN; ++qn)
                b[qn] = *reinterpret_cast<const f32x4*>(&Bs[k * SB + qn * 64 + tx * 4]);
            #pragma unroll
            for (int qm = 0; qm < RM; ++qm)
                #pragma unroll
                for (int qn = 0; qn < RN; ++qn)
                    #pragma unroll
                    for (int i = 0; i < 4; ++i)
                        #pragma unroll
                        for (int j = 0; j < 4; ++j)
                            acc[qm][qn][i][j] += a[qm][i] * b[qn][j];
        }
    }

    // Epilogue
    #pragma unroll
    for (int qn = 0; qn < RN; ++qn) {
        const int cbase = n0 + qn * 64 + tx * 4;
        float ca = 0.f, sa = 0.f;
        if (MODE == 1) {
            const int h = (n0 >> 6) + qn;   // head is constant per quadrant
            ca = cosf(angles[h]);
            sa = sinf(angles[h]);
        }
        #pragma unroll
        for (int qm = 0; qm < RM; ++qm) {
            #pragma unroll
            for (int i = 0; i < 4; ++i) {
                const int r = m0 + qm * 64 + ty * 4 + i;
                const int b = r >> 11;          // r / T_
                const int t = r & (T_ - 1);
                f32x4 v;
                #pragma unroll
                for (int j = 0; j < 4; ++j) v[j] = acc[qm][qn][i][j];
                if (MODE == 0) {
                    *reinterpret_cast<f32x4*>(&Cout[(size_t)r * Nld + cbase]) = v;
                } else if (MODE == 1) {
                    const int h = cbase >> 6;
                    const int d = cbase & 63;
                    f32x4 o;
                    o[0] = v[0] * ca - v[1] * sa;
                    o[1] = v[0] * sa + v[1] * ca;
                    o[2] = v[2] * ca - v[3] * sa;
                    o[3] = v[2] * sa + v[3] * ca;
                    *reinterpret_cast<f32x4*>(
                        &Cout[(((size_t)(b * H_ + h)) * T_ + t) * D_ + d]) = o;
                } else {
                    const int h = cbase >> 6;
                    const int d = cbase & 63;
                    *reinterpret_cast<f32x4*>(
                        &Cout[(((size_t)(b * KVH_ + h)) * T_ + t) * D_ + d]) = v;
                }
            }
        }
    }
}

// ---------------------------------------------------------------------------
// fp32 flash-style causal attention with ALiBi and "+1" softmax denominator.
//   Q: (B,H,T,D)  K,V: (B,KVH,T,D)  ->  O: (B,T,H*D)
// Grid: (T/64, B*H). Block: 256 threads (16x16), 64 queries per block.
// Online softmax: m,l running per row; final denom = 1 + l (exactly matches
// reference: e = exp(att - rowmax); att = e / (1 + sum e)).
// ---------------------------------------------------------------------------
__global__ __launch_bounds__(256, 2)
void flash_k(const float* __restrict__ Q, const float* __restrict__ K,
             const float* __restrict__ V, const float* __restrict__ slopes,
             float* __restrict__ O)
{
    constexpr int S = 68;   // padded stride (16B-aligned, low bank conflicts)
    __shared__ float Qs[64 * S];
    __shared__ float Ks[64 * S];
    __shared__ float Vs[64 * S];
    __shared__ float Ps[64 * S];

    const int tid = threadIdx.x;
    const int tx  = tid & 15;
    const int ty  = tid >> 4;
    const int bh  = blockIdx.y;
    const int b   = bh >> 4;
    const int h   = bh & 15;
    const int kvh = h >> 2;              // GQA: jnp.repeat -> h // (H/KVH)
    const int qt  = blockIdx.x;
    const int q0  = qt * 64;

    const float slope = expf(slopes[h]);

    const float* Qp = Q + (((size_t)(b * H_ + h)) * T_ + q0) * D_;
    const float* Kp = K + (((size_t)(b * KVH_ + kvh)) * T_) * D_;
    const float* Vp = V + (((size_t)(b * KVH_ + kvh)) * T_) * D_;

    // Load Q tile (64 x 64)
    #pragma unroll
    for (int it = 0; it < 4; ++it) {
        int idx = tid + it * 256;
        int row = idx >> 4;
        int c4  = (idx & 15) << 2;
        *reinterpret_cast<f32x4*>(&Qs[row * S + c4]) =
            *reinterpret_cast<const f32x4*>(Qp + row * 64 + c4);
    }

    float acc[4][4] = {};
    float mrow[4], lrow[4] = {};
    #pragma unroll
    for (int i = 0; i < 4; ++i) mrow[i] = -INFINITY;

    for (int j = 0; j <= qt; ++j) {
        __syncthreads();   // previous iteration's LDS reads done (also covers Qs)
        #pragma unroll
        for (int it = 0; it < 4; ++it) {
            int idx = tid + it * 256;
            int row = idx >> 4;
            int c4  = (idx & 15) << 2;
            *reinterpret_cast<f32x4*>(&Ks[row * S + c4]) =
                *reinterpret_cast<const f32x4*>(Kp + (j * 64 + row) * 64 + c4);
            *reinterpret_cast<f32x4*>(&Vs[row * S + c4]) =
                *reinterpret_cast<const f32x4*>(Vp + (j * 64 + row) * 64 + c4);
        }
        __syncthreads();

        // S = Q K^T  (4x4 per thread)
        float s[4][4] = {};
        #pragma unroll
        for (int d4 = 0; d4 < 16; ++d4) {
            f32x4 qv[4], kv[4];
            #pragma unroll
            for (int i = 0; i < 4; ++i)
                qv[i] = *reinterpret_cast<const f32x4*>(&Qs[(ty * 4 + i) * S + d4 * 4]);
            #pragma unroll
            for (int jj = 0; jj < 4; ++jj)
                kv[jj] = *reinterpret_cast<const f32x4*>(&Ks[(tx * 4 + jj) * S + d4 * 4]);
            #pragma unroll
            for (int i = 0; i < 4; ++i)
                #pragma unroll
                for (int jj = 0; jj < 4; ++jj)
                    #pragma unroll
                    for (int u = 0; u < 4; ++u)
                        s[i][jj] += qv[i][u] * kv[jj][u];
        }

        // ALiBi + causal mask + online softmax (row groups = 16 tx lanes)
        #pragma unroll
        for (int i = 0; i < 4; ++i) {
            const int qg = q0 + ty * 4 + i;
            float sv[4];
            float tmax = -INFINITY;
            #pragma unroll
            for (int jj = 0; jj < 4; ++jj) {
                const int kg = j * 64 + tx * 4 + jj;
                float a = s[i][jj] * 0.125f + slope * (float)(qg - kg);
                a = (kg <= qg) ? a : -INFINITY;
                sv[jj] = a;
                tmax = fmaxf(tmax, a);
            }
            #pragma unroll
            for (int off = 1; off < 16; off <<= 1)
                tmax = fmaxf(tmax, __shfl_xor(tmax, off));
            const float mnew  = fmaxf(mrow[i], tmax);
            const float scale = expf(mrow[i] - mnew);   // -inf -> 0 first tile
            float rsum = 0.f;
            #pragma unroll
            for (int jj = 0; jj < 4; ++jj) {
                const float p = expf(sv[jj] - mnew);    // masked -> 0
                sv[jj] = p;
                rsum += p;
            }
            #pragma unroll
            for (int off = 1; off < 16; off <<= 1)
                rsum += __shfl_xor(rsum, off);
            lrow[i] = lrow[i] * scale + rsum;
            mrow[i] = mnew;
            #pragma unroll
            for (int jj = 0; jj < 4; ++jj) acc[i][jj] *= scale;
            f32x4 pv;
            #pragma unroll
            for (int jj = 0; jj < 4; ++jj) pv[jj] = sv[jj];
            *reinterpret_cast<f32x4*>(&Ps[(ty * 4 + i) * S + tx * 4]) = pv;
        }
        __syncthreads();

        // acc += P @ V   (thread owns rows ty*4.., cols tx*4..)
        #pragma unroll
        for (int k4 = 0; k4 < 16; ++k4) {
            f32x4 pr[4], vr[4];
            #pragma unroll
            for (int i = 0; i < 4; ++i)
                pr[i] = *reinterpret_cast<const f32x4*>(&Ps[(ty * 4 + i) * S + k4 * 4]);
            #pragma unroll
            for (int u = 0; u < 4; ++u)
                vr[u] = *reinterpret_cast<const f32x4*>(&Vs[(k4 * 4 + u) * S + tx * 4]);
            #pragma unroll
            for (int i = 0; i < 4; ++i)
                #pragma unroll
                for (int u = 0; u < 4; ++u)
                    #pragma unroll
                    for (int jj = 0; jj < 4; ++jj)
                        acc[i][jj] += pr[i][u] * vr[u][jj];
        }
    }

    // Write (B, T, H*D) with denom = 1 + l
    #pragma unroll
    for (int i = 0; i < 4; ++i) {
        const float inv = 1.0f / (1.0f + lrow[i]);
        const int qg = q0 + ty * 4 + i;
        f32x4 o;
        #pragma unroll
        for (int jj = 0; jj < 4; ++jj) o[jj] = acc[i][jj] * inv;
        *reinterpret_cast<f32x4*>(
            &O[((size_t)b * T_ + qg) * (H_ * D_) + h * 64 + tx * 4]) = o;
    }
}

// ---------------------------------------------------------------------------
// Launcher. Workspace layout (floats):
//   Qb   : B*H*T*D     = 4,194,304   (B,H,T,D)
//   Kb   : B*KVH*T*D   = 1,048,576   (B,KVH,T,D)
//   Vb   : B*KVH*T*D   = 1,048,576
//   AttO : B*T*H*D     = 4,194,304   (B,T,H*D)
// Total 40 MiB. Everything read is written first each call (ws is re-poisoned).
// ---------------------------------------------------------------------------
extern "C" void kernel_launch(void* const* d_in, const int* in_sizes, int n_in,
                              void* d_out, int out_size, void* d_ws, size_t ws_size,
                              hipStream_t stream)
{
    const float* x      = (const float*)d_in[0];
    const float* Wq     = (const float*)d_in[1];
    const float* Wk     = (const float*)d_in[2];
    const float* Wv     = (const float*)d_in[3];
    const float* Wo     = (const float*)d_in[4];
    const float* ang    = (const float*)d_in[5];
    const float* slopes = (const float*)d_in[6];
    float* out = (float*)d_out;

    float* Qb   = (float*)d_ws;
    float* Kb   = Qb + (size_t)B_ * H_ * T_ * D_;
    float* Vb   = Kb + (size_t)B_ * KVH_ * T_ * D_;
    float* AttO = Vb + (size_t)B_ * KVH_ * T_ * D_;

    const int M = B_ * T_;   // 4096

    // Q = x_pos @ Wq  (+ phase rotation) -> (B,H,T,D)
    gemm_k<128, 128, 1><<<dim3(1024 / 128, M / 128), 256, 0, stream>>>(
        x, TOK_ + POS_, TOK_, Wq, POS_, H_ * D_, Qb, ang);
    // K = x_pos @ Wk -> (B,KVH,T,D)
    gemm_k<64, 64, 2><<<dim3(256 / 64, M / 64), 256, 0, stream>>>(
        x, TOK_ + POS_, TOK_, Wk, POS_, KVH_ * D_, Kb, nullptr);
    // V = x_tok @ Wv -> (B,KVH,T,D)
    gemm_k<64, 64, 2><<<dim3(256 / 64, M / 64), 256, 0, stream>>>(
        x, TOK_ + POS_, 0, Wv, TOK_, KVH_ * D_, Vb, nullptr);
    // Flash attention -> AttO (B,T,H*D)
    flash_k<<<dim3(T_ / 64, B_ * H_), 256, 0, stream>>>(Qb, Kb, Vb, slopes, AttO);
    // out = AttO @ Wo
    gemm_k<128, 128, 0><<<dim3(1024 / 128, M / 128), 256, 0, stream>>>(
        AttO, H_ * D_, 0, Wo, H_ * D_, TOK_ + POS_, out, nullptr);
}

// Round 3
// 469.106 us; speedup vs baseline: 2.1829x; 2.1829x over previous
//
#include <hip/hip_runtime.h>
#include <hip/hip_bf16.h>
#include <math.h>

// Problem constants (match reference)
#define B_   2
#define T_   2048
#define TOK_ 512
#define POS_ 512
#define H_   16
#define D_   64
#define KVH_ 4

typedef float f32x4 __attribute__((ext_vector_type(4)));
typedef short bf16x8 __attribute__((ext_vector_type(8)));
typedef unsigned short u16;
typedef u16 u16x4 __attribute__((ext_vector_type(4)));
typedef u16 u16x8 __attribute__((ext_vector_type(8)));

// RNE float -> bf16 bits
__device__ inline u16 f2bf(float f) {
    union { float f; unsigned u; } v; v.f = f;
    unsigned r = v.u + 0x7FFFu + ((v.u >> 16) & 1u);
    return (u16)(r >> 16);
}

// ---------------------------------------------------------------------------
// Generic fp32 tiled GEMM: C[M,N] = A[M,K] @ W[K,N]  (fp32 compute)
// MODE 0: fp32 write, C row-major ld = Nld (out = attO @ Wo)
// MODE 1: Q projection -> phase rotation, write bf16 (B,H,T,D)
// MODE 2: K/V projection -> write bf16 (B,KVH,T,D)
// ---------------------------------------------------------------------------
template<int BM, int BN, int MODE>
__global__ __launch_bounds__(256, 2)
void gemm_k(const float* __restrict__ A, int lda, int aoff,
            const float* __restrict__ W, int Ktot, int Nld,
            void* __restrict__ CoutV, const float* __restrict__ angles)
{
    constexpr int RM = BM / 64;
    constexpr int RN = BN / 64;
    constexpr int SA = BM + 4;
    constexpr int SB = BN + 4;
    __shared__ float As[16 * SA];   // transposed: As[k][m]
    __shared__ float Bs[16 * SB];   // Bs[k][n]

    const int tid = threadIdx.x;
    const int tx  = tid & 15;
    const int ty  = tid >> 4;
    const int m0  = blockIdx.y * BM;
    const int n0  = blockIdx.x * BN;

    float acc[RM][RN][4][4] = {};

    for (int k0 = 0; k0 < Ktot; k0 += 16) {
        __syncthreads();
        #pragma unroll
        for (int it = 0; it < BM / 64; ++it) {
            int idx = tid + it * 256;
            int row = idx >> 2;
            int k4  = (idx & 3) << 2;
            f32x4 av = *reinterpret_cast<const f32x4*>(
                A + (size_t)(m0 + row) * lda + aoff + k0 + k4);
            #pragma unroll
            for (int u = 0; u < 4; ++u) As[(k4 + u) * SA + row] = av[u];
        }
        #pragma unroll
        for (int it = 0; it < BN / 64; ++it) {
            int idx = tid + it * 256;
            int kr  = idx / (BN / 4);
            int c4  = (idx % (BN / 4)) << 2;
            *reinterpret_cast<f32x4*>(&Bs[kr * SB + c4]) =
                *reinterpret_cast<const f32x4*>(
                    W + (size_t)(k0 + kr) * Nld + n0 + c4);
        }
        __syncthreads();

        #pragma unroll
        for (int k = 0; k < 16; ++k) {
            f32x4 a[RM], b[RN];
            #pragma unroll
            for (int qm = 0; qm < RM; ++qm)
                a[qm] = *reinterpret_cast<const f32x4*>(&As[k * SA + qm * 64 + ty * 4]);
            #pragma unroll
            for (int qn = 0; qn < RN; ++qn)
                b[qn] = *reinterpret_cast<const f32x4*>(&Bs[k * SB + qn * 64 + tx * 4]);
            #pragma unroll
            for (int qm = 0; qm < RM; ++qm)
                #pragma unroll
                for (int qn = 0; qn < RN; ++qn)
                    #pragma unroll
                    for (int i = 0; i < 4; ++i)
                        #pragma unroll
                        for (int j = 0; j < 4; ++j)
                            acc[qm][qn][i][j] += a[qm][i] * b[qn][j];
        }
    }

    #pragma unroll
    for (int qn = 0; qn < RN; ++qn) {
        const int cbase = n0 + qn * 64 + tx * 4;
        float ca = 0.f, sa = 0.f;
        if (MODE == 1) {
            const int hh = (n0 >> 6) + qn;
            ca = cosf(angles[hh]);
            sa = sinf(angles[hh]);
        }
        #pragma unroll
        for (int qm = 0; qm < RM; ++qm) {
            #pragma unroll
            for (int i = 0; i < 4; ++i) {
                const int r = m0 + qm * 64 + ty * 4 + i;
                const int b = r >> 11;          // r / T_
                const int t = r & (T_ - 1);
                f32x4 v;
                #pragma unroll
                for (int j = 0; j < 4; ++j) v[j] = acc[qm][qn][i][j];
                if (MODE == 0) {
                    *reinterpret_cast<f32x4*>(
                        &((float*)CoutV)[(size_t)r * Nld + cbase]) = v;
                } else if (MODE == 1) {
                    const int h = cbase >> 6;
                    const int d = cbase & 63;
                    u16x4 o;
                    o[0] = f2bf(v[0] * ca - v[1] * sa);
                    o[1] = f2bf(v[0] * sa + v[1] * ca);
                    o[2] = f2bf(v[2] * ca - v[3] * sa);
                    o[3] = f2bf(v[2] * sa + v[3] * ca);
                    *reinterpret_cast<u16x4*>(
                        &((u16*)CoutV)[(((size_t)(b * H_ + h)) * T_ + t) * D_ + d]) = o;
                } else {
                    const int h = cbase >> 6;
                    const int d = cbase & 63;
                    u16x4 o;
                    #pragma unroll
                    for (int j = 0; j < 4; ++j) o[j] = f2bf(v[j]);
                    *reinterpret_cast<u16x4*>(
                        &((u16*)CoutV)[(((size_t)(b * KVH_ + h)) * T_ + t) * D_ + d]) = o;
                }
            }
        }
    }
}

// ---------------------------------------------------------------------------
// MFMA bf16 flash attention (causal, ALiBi, "+1" softmax denominator).
//   Q: (B,H,T,D) bf16   K,V: (B,KVH,T,D) bf16   ->  O: (B,T,H*D) fp32
// Grid (T/64, B*H); block 256 = 4 waves; wave w owns q-rows [w*16, w*16+16).
// mfma_f32_16x16x32_bf16: A row=lane&15, k=(lane>>4)*8+e (both operands load
// k identically, so any within-group k permutation cancels).
// C/D: col=lane&15, row=(lane>>4)*4+j  [HW-verified m89].
// LDS tiles are 64 rows x 128 B; all accesses XOR-swizzled byte^=(row&7)<<4
// (G4-measured fix for the 128B-row b128-read bank-conflict geometry).
// ---------------------------------------------------------------------------
__global__ __launch_bounds__(256, 3)
void flash_mfma(const u16* __restrict__ Q, const u16* __restrict__ K,
                const u16* __restrict__ V, const float* __restrict__ slopes,
                float* __restrict__ O)
{
    __shared__ __align__(16) unsigned char lds[24576];
    unsigned char* Ks = lds;              // K tile: [key][d]  64x128B
    unsigned char* Vt = lds + 8192;       // V tile transposed: [d][key] 64x128B
    unsigned char* Ps = lds + 16384;      // P tiles: per-wave [16][64] bf16

    const int tid  = threadIdx.x;
    const int lane = tid & 63;
    const int w    = tid >> 6;
    const int lr   = lane & 15;
    const int lg   = lane >> 4;

    const int bh  = blockIdx.y;
    const int b   = bh >> 4;
    const int h   = bh & 15;
    const int kvh = h >> 2;              // GQA: h // (H/KVH)
    const int qt  = blockIdx.x;
    const int q0  = qt * 64;

    const float slope = expf(slopes[h]);

    const u16* Qp = Q + (((size_t)(b * H_ + h)) * T_ + q0 + w * 16) * D_;
    const u16* Kp = K + ((size_t)(b * KVH_ + kvh)) * T_ * D_;
    const u16* Vp = V + ((size_t)(b * KVH_ + kvh)) * T_ * D_;

    // Q A-fragments (row = lr, k = lg*8+e), two K=32 halves of D=64
    const bf16x8 qa0 = *reinterpret_cast<const bf16x8*>(Qp + lr * D_ + lg * 8);
    const bf16x8 qa1 = *reinterpret_cast<const bf16x8*>(Qp + lr * D_ + 32 + lg * 8);

    f32x4 acc[4] = {};                   // O frags: 4 d-subtiles of 16
    float mrow[4], lrow[4];
    #pragma unroll
    for (int j = 0; j < 4; ++j) { mrow[j] = -INFINITY; lrow[j] = 0.f; }

    unsigned char* Pw = Ps + w * 2048;   // 16 rows x 128 B, wave-private

    for (int jt = 0; jt <= qt; ++jt) {
        const int kv0 = jt * 64;
        __syncthreads();                 // all waves done reading previous tile
        // ---- stage K (row-major bf16) + V (transposed) into LDS, swizzled
        #pragma unroll
        for (int it = 0; it < 2; ++it) {
            int lin = tid + it * 256;
            // K: 512 chunks of 8 bf16
            int row = lin >> 3;
            int c16 = (lin & 7) * 16;    // byte col
            u16x8 kv = *reinterpret_cast<const u16x8*>(
                Kp + (size_t)(kv0 + row) * D_ + (lin & 7) * 8);
            *reinterpret_cast<u16x8*>(Ks + ((row * 128 + c16) ^ ((row & 7) << 4))) = kv;
            // V: key = lin&63 (=lane -> 2-way write conflicts only), 8 d's
            int key = lin & 63;
            int d8  = (lin >> 6) * 8;
            u16x8 vv = *reinterpret_cast<const u16x8*>(
                Vp + (size_t)(kv0 + key) * D_ + d8);
            #pragma unroll
            for (int e = 0; e < 8; ++e) {
                int d = d8 + e;
                *reinterpret_cast<u16*>(
                    Vt + ((d * 128 + key * 2) ^ ((d & 7) << 4))) = (u16)vv[e];
            }
        }
        __syncthreads();

        // ---- S = Q K^T : 4 key-subtiles x 2 d-halves
        f32x4 s[4];
        #pragma unroll
        for (int n = 0; n < 4; ++n) {
            int krow = n * 16 + lr;
            int swz  = (krow & 7) << 4;
            bf16x8 kb0 = *reinterpret_cast<bf16x8*>(Ks + ((krow * 128 + lg * 16) ^ swz));
            bf16x8 kb1 = *reinterpret_cast<bf16x8*>(Ks + ((krow * 128 + 64 + lg * 16) ^ swz));
            f32x4 z = {};
            z    = __builtin_amdgcn_mfma_f32_16x16x32_bf16(qa0, kb0, z, 0, 0, 0);
            s[n] = __builtin_amdgcn_mfma_f32_16x16x32_bf16(qa1, kb1, z, 0, 0, 0);
        }

        // ---- online softmax; rows r = lg*4+j, cols kv0 + n*16 + lr
        const int qbase = q0 + w * 16 + lg * 4;
        #pragma unroll
        for (int j = 0; j < 4; ++j) {
            const int qr = qbase + j;
            float a[4];
            float tmax = -INFINITY;
            #pragma unroll
            for (int n = 0; n < 4; ++n) {
                int kg = kv0 + n * 16 + lr;
                float vsc = s[n][j] * 0.125f + slope * (float)(qr - kg);
                vsc = (kg <= qr) ? vsc : -INFINITY;
                a[n] = vsc;
                tmax = fmaxf(tmax, vsc);
            }
            #pragma unroll
            for (int off = 1; off < 16; off <<= 1)
                tmax = fmaxf(tmax, __shfl_xor(tmax, off));
            const float mnew = fmaxf(mrow[j], tmax);
            const float sc   = __expf(mrow[j] - mnew);   // -inf -> 0 first tile
            float rsum = 0.f;
            u16 pb[4];
            #pragma unroll
            for (int n = 0; n < 4; ++n) {
                float p = __expf(a[n] - mnew);           // masked -> 0
                rsum += p;
                pb[n] = f2bf(p);
            }
            #pragma unroll
            for (int off = 1; off < 16; off <<= 1)
                rsum += __shfl_xor(rsum, off);
            lrow[j] = lrow[j] * sc + rsum;
            mrow[j] = mnew;
            #pragma unroll
            for (int dt = 0; dt < 4; ++dt) acc[dt][j] *= sc;
            const int prow = lg * 4 + j;
            #pragma unroll
            for (int n = 0; n < 4; ++n)
                *reinterpret_cast<u16*>(
                    Pw + ((prow * 128 + (n * 16 + lr) * 2) ^ ((prow & 7) << 4))) = pb[n];
        }

        // ---- O += P V   (Pw is wave-private; lgkmcnt ordering within wave)
        #pragma unroll
        for (int kh = 0; kh < 2; ++kh) {
            bf16x8 pa = *reinterpret_cast<bf16x8*>(
                Pw + ((lr * 128 + kh * 64 + lg * 16) ^ ((lr & 7) << 4)));
            #pragma unroll
            for (int dt = 0; dt < 4; ++dt) {
                int drow = dt * 16 + lr;
                bf16x8 vb = *reinterpret_cast<bf16x8*>(
                    Vt + ((drow * 128 + kh * 64 + lg * 16) ^ ((drow & 7) << 4)));
                acc[dt] = __builtin_amdgcn_mfma_f32_16x16x32_bf16(pa, vb, acc[dt], 0, 0, 0);
            }
        }
    }

    // ---- epilogue: denom = 1 + l, write fp32 (B,T,H*D)
    float* Op = O + ((size_t)b * T_ + q0 + w * 16) * (H_ * D_) + h * 64;
    #pragma unroll
    for (int j = 0; j < 4; ++j) {
        const float inv = 1.0f / (1.0f + lrow[j]);
        const int r = lg * 4 + j;
        #pragma unroll
        for (int dt = 0; dt < 4; ++dt)
            Op[(size_t)r * (H_ * D_) + dt * 16 + lr] = acc[dt][j] * inv;
    }
}

// ---------------------------------------------------------------------------
// Launcher. Workspace (bytes): Qb bf16 8MB | Kb bf16 2MB | Vb bf16 2MB |
// AttO fp32 16MB. All ws regions fully written each call.
// ---------------------------------------------------------------------------
extern "C" void kernel_launch(void* const* d_in, const int* in_sizes, int n_in,
                              void* d_out, int out_size, void* d_ws, size_t ws_size,
                              hipStream_t stream)
{
    const float* x      = (const float*)d_in[0];
    const float* Wq     = (const float*)d_in[1];
    const float* Wk     = (const float*)d_in[2];
    const float* Wv     = (const float*)d_in[3];
    const float* Wo     = (const float*)d_in[4];
    const float* ang    = (const float*)d_in[5];
    const float* slopes = (const float*)d_in[6];
    float* out = (float*)d_out;

    u16* Qb = (u16*)d_ws;
    u16* Kb = Qb + (size_t)B_ * H_ * T_ * D_;
    u16* Vb = Kb + (size_t)B_ * KVH_ * T_ * D_;
    float* AttO = (float*)(Vb + (size_t)B_ * KVH_ * T_ * D_);

    const int M = B_ * T_;   // 4096

    // Q = x_pos @ Wq (+rotation) -> bf16 (B,H,T,D)
    gemm_k<128, 128, 1><<<dim3(1024 / 128, M / 128), 256, 0, stream>>>(
        x, TOK_ + POS_, TOK_, Wq, POS_, H_ * D_, Qb, ang);
    // K = x_pos @ Wk -> bf16 (B,KVH,T,D)
    gemm_k<64, 64, 2><<<dim3(256 / 64, M / 64), 256, 0, stream>>>(
        x, TOK_ + POS_, TOK_, Wk, POS_, KVH_ * D_, Kb, nullptr);
    // V = x_tok @ Wv -> bf16 (B,KVH,T,D)
    gemm_k<64, 64, 2><<<dim3(256 / 64, M / 64), 256, 0, stream>>>(
        x, TOK_ + POS_, 0, Wv, TOK_, KVH_ * D_, Vb, nullptr);
    // Flash attention (MFMA bf16) -> AttO fp32 (B,T,H*D)
    flash_mfma<<<dim3(T_ / 64, B_ * H_), 256, 0, stream>>>(Qb, Kb, Vb, slopes, AttO);
    // out = AttO @ Wo (fp32)
    gemm_k<128, 128, 0><<<dim3(1024 / 128, M / 128), 256, 0, stream>>>(
        AttO, H_ * D_, 0, Wo, H_ * D_, TOK_ + POS_, out, nullptr);
}

// Round 10
// 290.935 us; speedup vs baseline: 3.5197x; 1.6124x over previous
//
#include <hip/hip_runtime.h>
#include <hip/hip_bf16.h>
#include <math.h>

// Problem constants (match reference)
#define B_   2
#define T_   2048
#define TOK_ 512
#define POS_ 512
#define H_   16
#define D_   64
#define KVH_ 4

typedef float f32x4 __attribute__((ext_vector_type(4)));
typedef short bf16x8 __attribute__((ext_vector_type(8)));
typedef unsigned short u16;
typedef u16 u16x4 __attribute__((ext_vector_type(4)));
typedef u16 u16x8 __attribute__((ext_vector_type(8)));

// RNE float -> bf16 bits
__device__ inline u16 f2bf(float f) {
    union { float f; unsigned u; } v; v.f = f;
    unsigned r = v.u + 0x7FFFu + ((v.u >> 16) & 1u);
    return (u16)(r >> 16);
}

// ---------------------------------------------------------------------------
// x (fp32, M x 1024) -> xb (bf16). 4 elems/thread.
// ---------------------------------------------------------------------------
__global__ void cvt_x(const float* __restrict__ X, u16* __restrict__ Xb) {
    int i = (blockIdx.x * 256 + threadIdx.x) * 4;
    f32x4 v = *reinterpret_cast<const f32x4*>(X + i);
    u16x4 o;
    #pragma unroll
    for (int u = 0; u < 4; ++u) o[u] = f2bf(v[u]);
    *reinterpret_cast<u16x4*>(Xb + i) = o;
}

// ---------------------------------------------------------------------------
// W (K x N fp32, row-major) -> WT (N x K bf16). 32x32 LDS tile.
// ---------------------------------------------------------------------------
__global__ void transp_k(const float* __restrict__ W, u16* __restrict__ WT,
                         int K, int N) {
    __shared__ float t[32][33];
    const int tid = threadIdx.x;
    const int k0 = blockIdx.y * 32, n0 = blockIdx.x * 32;
    const int r = tid >> 3, c4 = (tid & 7) * 4;
    f32x4 v = *reinterpret_cast<const f32x4*>(W + (size_t)(k0 + r) * N + n0 + c4);
    #pragma unroll
    for (int u = 0; u < 4; ++u) t[r][c4 + u] = v[u];
    __syncthreads();
    u16x4 o;
    #pragma unroll
    for (int u = 0; u < 4; ++u) o[u] = f2bf(t[c4 + u][r]);
    *reinterpret_cast<u16x4*>(WT + (size_t)(n0 + r) * K + k0 + c4) = o;
}

// ---------------------------------------------------------------------------
// bf16 MFMA GEMM: C[M,N] = A[M,K] @ W[K,N], W given pre-transposed (Bt: N x K).
// 128x128 tile, BK=32, 4 waves in 2x2, each wave a 64x64 sub-tile of 4x4
// 16x16 frags. Fragment mapping HW-validated in flash_mfma (round 3):
//   A: row=lane&15, k=(lane>>4)*8+e ; B: col=lane&15, same k ;
//   C/D: col=lane&15, row=(lane>>4)*4+j.
// LDS rows stride 80 B (16B-aligned, breaks the stride-64B bank geometry).
// MODE 0: fp32 write to out[m][1024] (Wo GEMM)
// MODE 1: phase-rotate pairs via __shfl_xor(.,1), write bf16 (B,H,T,D)
// MODE 2: write bf16 (B,KVH,T,D)
// ---------------------------------------------------------------------------
template<int MODE>
__global__ __launch_bounds__(256, 2)
void mfma_gemm(const u16* __restrict__ A, int lda, int aoff,
               const u16* __restrict__ Bt, int Ktot,
               void* __restrict__ Cout, const float* __restrict__ angles)
{
    __shared__ __align__(16) unsigned char lds[20480];
    unsigned char* As = lds;            // 128 rows x 32 bf16, stride 80 B
    unsigned char* Bs = lds + 10240;    // 128 rows x 32 bf16, stride 80 B

    const int tid  = threadIdx.x;
    const int lane = tid & 63;
    const int w    = tid >> 6;
    const int wm   = w >> 1, wn = w & 1;
    const int lr   = lane & 15, lg = lane >> 4;
    const int m0   = blockIdx.y * 128;
    const int n0   = blockIdx.x * 128;

    f32x4 acc[4][4] = {};

    for (int k0 = 0; k0 < Ktot; k0 += 32) {
        __syncthreads();
        #pragma unroll
        for (int p = 0; p < 2; ++p) {
            int lin = tid + p * 256;          // 0..511
            int row = lin >> 2;               // 0..127
            int kc  = (lin & 3) * 8;          // 0,8,16,24
            u16x8 av = *reinterpret_cast<const u16x8*>(
                A + (size_t)(m0 + row) * lda + aoff + k0 + kc);
            *reinterpret_cast<u16x8*>(As + row * 80 + kc * 2) = av;
            u16x8 bv = *reinterpret_cast<const u16x8*>(
                Bt + (size_t)(n0 + row) * Ktot + k0 + kc);
            *reinterpret_cast<u16x8*>(Bs + row * 80 + kc * 2) = bv;
        }
        __syncthreads();

        bf16x8 af[4], bfr[4];
        #pragma unroll
        for (int mt = 0; mt < 4; ++mt)
            af[mt] = *reinterpret_cast<bf16x8*>(
                As + (wm * 64 + mt * 16 + lr) * 80 + lg * 16);
        #pragma unroll
        for (int nt = 0; nt < 4; ++nt)
            bfr[nt] = *reinterpret_cast<bf16x8*>(
                Bs + (wn * 64 + nt * 16 + lr) * 80 + lg * 16);
        #pragma unroll
        for (int mt = 0; mt < 4; ++mt)
            #pragma unroll
            for (int nt = 0; nt < 4; ++nt)
                acc[mt][nt] = __builtin_amdgcn_mfma_f32_16x16x32_bf16(
                    af[mt], bfr[nt], acc[mt][nt], 0, 0, 0);
    }

    // Epilogue. m = m0+wm*64+mt*16+lg*4+j ; n = n0+wn*64+nt*16+lr
    #pragma unroll
    for (int nt = 0; nt < 4; ++nt) {
        const int nbase = n0 + wn * 64 + nt * 16;   // multiple of 16
        float ca = 0.f, sa = 0.f;
        if (MODE == 1) {
            const int h = nbase >> 6;               // constant across lr (<64)
            ca = cosf(angles[h]);
            sa = sinf(angles[h]);
        }
        #pragma unroll
        for (int mt = 0; mt < 4; ++mt) {
            #pragma unroll
            for (int j = 0; j < 4; ++j) {
                const int m = m0 + wm * 64 + mt * 16 + lg * 4 + j;
                const int n = nbase + lr;
                const float v = acc[mt][nt][j];
                if (MODE == 0) {
                    ((float*)Cout)[(size_t)m * (TOK_ + POS_) + n] = v;
                } else if (MODE == 1) {
                    const float p = __shfl_xor(v, 1);   // partner column n^1
                    const float o = (lr & 1) ? (p * sa + v * ca)
                                             : (v * ca - p * sa);
                    const int b = m >> 11, t = m & (T_ - 1);
                    const int h = n >> 6, d = n & 63;
                    ((u16*)Cout)[(((size_t)(b * H_ + h)) * T_ + t) * D_ + d] = f2bf(o);
                } else {
                    const int b = m >> 11, t = m & (T_ - 1);
                    const int h = n >> 6, d = n & 63;
                    ((u16*)Cout)[(((size_t)(b * KVH_ + h)) * T_ + t) * D_ + d] = f2bf(v);
                }
            }
        }
    }
}

// ---------------------------------------------------------------------------
// MFMA bf16 flash attention (unchanged from validated round-3 version except
// the output is now written as bf16 (B,T,H*D) to feed the Wo MFMA GEMM).
// ---------------------------------------------------------------------------
__global__ __launch_bounds__(256, 3)
void flash_mfma(const u16* __restrict__ Q, const u16* __restrict__ K,
                const u16* __restrict__ V, const float* __restrict__ slopes,
                u16* __restrict__ O)
{
    __shared__ __align__(16) unsigned char lds[24576];
    unsigned char* Ks = lds;              // K tile: [key][d]  64x128B
    unsigned char* Vt = lds + 8192;       // V tile transposed: [d][key] 64x128B
    unsigned char* Ps = lds + 16384;      // P tiles: per-wave [16][64] bf16

    const int tid  = threadIdx.x;
    const int lane = tid & 63;
    const int w    = tid >> 6;
    const int lr   = lane & 15;
    const int lg   = lane >> 4;

    const int bh  = blockIdx.y;
    const int b   = bh >> 4;
    const int h   = bh & 15;
    const int kvh = h >> 2;              // GQA: h // (H/KVH)
    const int qt  = blockIdx.x;
    const int q0  = qt * 64;

    const float slope = expf(slopes[h]);

    const u16* Qp = Q + (((size_t)(b * H_ + h)) * T_ + q0 + w * 16) * D_;
    const u16* Kp = K + ((size_t)(b * KVH_ + kvh)) * T_ * D_;
    const u16* Vp = V + ((size_t)(b * KVH_ + kvh)) * T_ * D_;

    const bf16x8 qa0 = *reinterpret_cast<const bf16x8*>(Qp + lr * D_ + lg * 8);
    const bf16x8 qa1 = *reinterpret_cast<const bf16x8*>(Qp + lr * D_ + 32 + lg * 8);

    f32x4 acc[4] = {};
    float mrow[4], lrow[4];
    #pragma unroll
    for (int j = 0; j < 4; ++j) { mrow[j] = -INFINITY; lrow[j] = 0.f; }

    unsigned char* Pw = Ps + w * 2048;

    for (int jt = 0; jt <= qt; ++jt) {
        const int kv0 = jt * 64;
        __syncthreads();
        #pragma unroll
        for (int it = 0; it < 2; ++it) {
            int lin = tid + it * 256;
            int row = lin >> 3;
            int c16 = (lin & 7) * 16;
            u16x8 kv = *reinterpret_cast<const u16x8*>(
                Kp + (size_t)(kv0 + row) * D_ + (lin & 7) * 8);
            *reinterpret_cast<u16x8*>(Ks + ((row * 128 + c16) ^ ((row & 7) << 4))) = kv;
            int key = lin & 63;
            int d8  = (lin >> 6) * 8;
            u16x8 vv = *reinterpret_cast<const u16x8*>(
                Vp + (size_t)(kv0 + key) * D_ + d8);
            #pragma unroll
            for (int e = 0; e < 8; ++e) {
                int d = d8 + e;
                *reinterpret_cast<u16*>(
                    Vt + ((d * 128 + key * 2) ^ ((d & 7) << 4))) = (u16)vv[e];
            }
        }
        __syncthreads();

        f32x4 s[4];
        #pragma unroll
        for (int n = 0; n < 4; ++n) {
            int krow = n * 16 + lr;
            int swz  = (krow & 7) << 4;
            bf16x8 kb0 = *reinterpret_cast<bf16x8*>(Ks + ((krow * 128 + lg * 16) ^ swz));
            bf16x8 kb1 = *reinterpret_cast<bf16x8*>(Ks + ((krow * 128 + 64 + lg * 16) ^ swz));
            f32x4 z = {};
            z    = __builtin_amdgcn_mfma_f32_16x16x32_bf16(qa0, kb0, z, 0, 0, 0);
            s[n] = __builtin_amdgcn_mfma_f32_16x16x32_bf16(qa1, kb1, z, 0, 0, 0);
        }

        const int qbase = q0 + w * 16 + lg * 4;
        #pragma unroll
        for (int j = 0; j < 4; ++j) {
            const int qr = qbase + j;
            float a[4];
            float tmax = -INFINITY;
            #pragma unroll
            for (int n = 0; n < 4; ++n) {
                int kg = kv0 + n * 16 + lr;
                float vsc = s[n][j] * 0.125f + slope * (float)(qr - kg);
                vsc = (kg <= qr) ? vsc : -INFINITY;
                a[n] = vsc;
                tmax = fmaxf(tmax, vsc);
            }
            #pragma unroll
            for (int off = 1; off < 16; off <<= 1)
                tmax = fmaxf(tmax, __shfl_xor(tmax, off));
            const float mnew = fmaxf(mrow[j], tmax);
            const float sc   = __expf(mrow[j] - mnew);
            float rsum = 0.f;
            u16 pb[4];
            #pragma unroll
            for (int n = 0; n < 4; ++n) {
                float p = __expf(a[n] - mnew);
                rsum += p;
                pb[n] = f2bf(p);
            }
            #pragma unroll
            for (int off = 1; off < 16; off <<= 1)
                rsum += __shfl_xor(rsum, off);
            lrow[j] = lrow[j] * sc + rsum;
            mrow[j] = mnew;
            #pragma unroll
            for (int dt = 0; dt < 4; ++dt) acc[dt][j] *= sc;
            const int prow = lg * 4 + j;
            #pragma unroll
            for (int n = 0; n < 4; ++n)
                *reinterpret_cast<u16*>(
                    Pw + ((prow * 128 + (n * 16 + lr) * 2) ^ ((prow & 7) << 4))) = pb[n];
        }

        #pragma unroll
        for (int kh = 0; kh < 2; ++kh) {
            bf16x8 pa = *reinterpret_cast<bf16x8*>(
                Pw + ((lr * 128 + kh * 64 + lg * 16) ^ ((lr & 7) << 4)));
            #pragma unroll
            for (int dt = 0; dt < 4; ++dt) {
                int drow = dt * 16 + lr;
                bf16x8 vb = *reinterpret_cast<bf16x8*>(
                    Vt + ((drow * 128 + kh * 64 + lg * 16) ^ ((drow & 7) << 4)));
                acc[dt] = __builtin_amdgcn_mfma_f32_16x16x32_bf16(pa, vb, acc[dt], 0, 0, 0);
            }
        }
    }

    u16* Op = O + ((size_t)b * T_ + q0 + w * 16) * (H_ * D_) + h * 64;
    #pragma unroll
    for (int j = 0; j < 4; ++j) {
        const float inv = 1.0f / (1.0f + lrow[j]);
        const int r = lg * 4 + j;
        #pragma unroll
        for (int dt = 0; dt < 4; ++dt)
            Op[(size_t)r * (H_ * D_) + dt * 16 + lr] = f2bf(acc[dt][j] * inv);
    }
}

// ---------------------------------------------------------------------------
// Launcher. ws layout (u16 elems): xb 4M | Qb 4M | Kb 1M | Vb 1M | AttO 4M |
// WqT 512K | WkT 128K | WvT 128K | WoT 1M  (~31.7 MB). All regions written
// every call before read (ws is re-poisoned each timed launch).
// ---------------------------------------------------------------------------
extern "C" void kernel_launch(void* const* d_in, const int* in_sizes, int n_in,
                              void* d_out, int out_size, void* d_ws, size_t ws_size,
                              hipStream_t stream)
{
    const float* x      = (const float*)d_in[0];
    const float* Wq     = (const float*)d_in[1];
    const float* Wk     = (const float*)d_in[2];
    const float* Wv     = (const float*)d_in[3];
    const float* Wo     = (const float*)d_in[4];
    const float* ang    = (const float*)d_in[5];
    const float* slopes = (const float*)d_in[6];
    float* out = (float*)d_out;

    u16* xb   = (u16*)d_ws;
    u16* Qb   = xb   + (size_t)4096 * 1024;
    u16* Kb   = Qb   + (size_t)B_ * H_ * T_ * D_;
    u16* Vb   = Kb   + (size_t)B_ * KVH_ * T_ * D_;
    u16* AttO = Vb   + (size_t)B_ * KVH_ * T_ * D_;
    u16* WqT  = AttO + (size_t)4096 * 1024;
    u16* WkT  = WqT  + (size_t)1024 * 512;
    u16* WvT  = WkT  + (size_t)256 * 512;
    u16* WoT  = WvT  + (size_t)256 * 512;

    // Prologue: convert x, transpose+convert weights
    cvt_x<<<4096, 256, 0, stream>>>(x, xb);
    transp_k<<<dim3(1024 / 32, 512 / 32), 256, 0, stream>>>(Wq, WqT, 512, 1024);
    transp_k<<<dim3(256 / 32, 512 / 32), 256, 0, stream>>>(Wk, WkT, 512, 256);
    transp_k<<<dim3(256 / 32, 512 / 32), 256, 0, stream>>>(Wv, WvT, 512, 256);
    transp_k<<<dim3(1024 / 32, 1024 / 32), 256, 0, stream>>>(Wo, WoT, 1024, 1024);

    // Projections (bf16 MFMA)
    mfma_gemm<1><<<dim3(8, 32), 256, 0, stream>>>(xb, 1024, 512, WqT, 512, Qb, ang);
    mfma_gemm<2><<<dim3(2, 32), 256, 0, stream>>>(xb, 1024, 512, WkT, 512, Kb, nullptr);
    mfma_gemm<2><<<dim3(2, 32), 256, 0, stream>>>(xb, 1024, 0,   WvT, 512, Vb, nullptr);

    // Flash attention -> AttO bf16 (B,T,H*D)
    flash_mfma<<<dim3(T_ / 64, B_ * H_), 256, 0, stream>>>(Qb, Kb, Vb, slopes, AttO);

    // out = AttO @ Wo (bf16 MFMA, fp32 out)
    mfma_gemm<0><<<dim3(8, 32), 256, 0, stream>>>(AttO, 1024, 0, WoT, 1024, out, nullptr);
}

// Round 12
// 239.606 us; speedup vs baseline: 4.2736x; 1.2142x over previous
//
#include <hip/hip_runtime.h>
#include <hip/hip_bf16.h>
#include <math.h>

// Problem constants (match reference)
#define B_   2
#define T_   2048
#define TOK_ 512
#define POS_ 512
#define H_   16
#define D_   64
#define KVH_ 4

typedef float f32x4 __attribute__((ext_vector_type(4)));
typedef short bf16x8 __attribute__((ext_vector_type(8)));
typedef unsigned short u16;
typedef u16 u16x4 __attribute__((ext_vector_type(4)));
typedef u16 u16x8 __attribute__((ext_vector_type(8)));

// RNE float -> bf16 bits
__device__ inline u16 f2bf(float f) {
    union { float f; unsigned u; } v; v.f = f;
    unsigned r = v.u + 0x7FFFu + ((v.u >> 16) & 1u);
    return (u16)(r >> 16);
}

// ---------------------------------------------------------------------------
// x (fp32, M x 1024) -> xb (bf16). 4 elems/thread.
// ---------------------------------------------------------------------------
__global__ void cvt_x(const float* __restrict__ X, u16* __restrict__ Xb) {
    int i = (blockIdx.x * 256 + threadIdx.x) * 4;
    f32x4 v = *reinterpret_cast<const f32x4*>(X + i);
    u16x4 o;
    #pragma unroll
    for (int u = 0; u < 4; ++u) o[u] = f2bf(v[u]);
    *reinterpret_cast<u16x4*>(Xb + i) = o;
}

// ---------------------------------------------------------------------------
// W (K x N fp32, row-major) -> WT (N x K bf16). 32x32 LDS tile.
// ---------------------------------------------------------------------------
__global__ void transp_k(const float* __restrict__ W, u16* __restrict__ WT,
                         int K, int N) {
    __shared__ float t[32][33];
    const int tid = threadIdx.x;
    const int k0 = blockIdx.y * 32, n0 = blockIdx.x * 32;
    const int r = tid >> 3, c4 = (tid & 7) * 4;
    f32x4 v = *reinterpret_cast<const f32x4*>(W + (size_t)(k0 + r) * N + n0 + c4);
    #pragma unroll
    for (int u = 0; u < 4; ++u) t[r][c4 + u] = v[u];
    __syncthreads();
    u16x4 o;
    #pragma unroll
    for (int u = 0; u < 4; ++u) o[u] = f2bf(t[c4 + u][r]);
    *reinterpret_cast<u16x4*>(WT + (size_t)(n0 + r) * K + k0 + c4) = o;
}

// ---------------------------------------------------------------------------
// bf16 MFMA GEMM: C[M,N] = A[M,K] @ W[K,N], W given pre-transposed (Bt: N x K).
// 128x128 tile, BK=32, 4 waves in 2x2, each wave a 64x64 sub-tile of 4x4
// 16x16 frags. Fragment mapping HW-validated (rounds 3/10):
//   A: row=lane&15, k=(lane>>4)*8+e ; B: col=lane&15, same k ;
//   C/D: col=lane&15, row=(lane>>4)*4+j.
// LDS rows stride 80 B (16B-aligned, breaks the stride-64B bank geometry).
// MODE 0: fp32 write to out[m][1024] (Wo GEMM)
// MODE 1: phase-rotate pairs via __shfl_xor(.,1), write bf16 (B,H,T,D)
// MODE 2: write bf16 (B,KVH,T,D)
// ---------------------------------------------------------------------------
template<int MODE>
__global__ __launch_bounds__(256, 2)
void mfma_gemm(const u16* __restrict__ A, int lda, int aoff,
               const u16* __restrict__ Bt, int Ktot,
               void* __restrict__ Cout, const float* __restrict__ angles)
{
    __shared__ __align__(16) unsigned char lds[20480];
    unsigned char* As = lds;            // 128 rows x 32 bf16, stride 80 B
    unsigned char* Bs = lds + 10240;    // 128 rows x 32 bf16, stride 80 B

    const int tid  = threadIdx.x;
    const int lane = tid & 63;
    const int w    = tid >> 6;
    const int wm   = w >> 1, wn = w & 1;
    const int lr   = lane & 15, lg = lane >> 4;
    const int m0   = blockIdx.y * 128;
    const int n0   = blockIdx.x * 128;

    f32x4 acc[4][4] = {};

    for (int k0 = 0; k0 < Ktot; k0 += 32) {
        __syncthreads();
        #pragma unroll
        for (int p = 0; p < 2; ++p) {
            int lin = tid + p * 256;          // 0..511
            int row = lin >> 2;               // 0..127
            int kc  = (lin & 3) * 8;          // 0,8,16,24
            u16x8 av = *reinterpret_cast<const u16x8*>(
                A + (size_t)(m0 + row) * lda + aoff + k0 + kc);
            *reinterpret_cast<u16x8*>(As + row * 80 + kc * 2) = av;
            u16x8 bv = *reinterpret_cast<const u16x8*>(
                Bt + (size_t)(n0 + row) * Ktot + k0 + kc);
            *reinterpret_cast<u16x8*>(Bs + row * 80 + kc * 2) = bv;
        }
        __syncthreads();

        bf16x8 af[4], bfr[4];
        #pragma unroll
        for (int mt = 0; mt < 4; ++mt)
            af[mt] = *reinterpret_cast<bf16x8*>(
                As + (wm * 64 + mt * 16 + lr) * 80 + lg * 16);
        #pragma unroll
        for (int nt = 0; nt < 4; ++nt)
            bfr[nt] = *reinterpret_cast<bf16x8*>(
                Bs + (wn * 64 + nt * 16 + lr) * 80 + lg * 16);
        #pragma unroll
        for (int mt = 0; mt < 4; ++mt)
            #pragma unroll
            for (int nt = 0; nt < 4; ++nt)
                acc[mt][nt] = __builtin_amdgcn_mfma_f32_16x16x32_bf16(
                    af[mt], bfr[nt], acc[mt][nt], 0, 0, 0);
    }

    // Epilogue. m = m0+wm*64+mt*16+lg*4+j ; n = n0+wn*64+nt*16+lr
    #pragma unroll
    for (int nt = 0; nt < 4; ++nt) {
        const int nbase = n0 + wn * 64 + nt * 16;   // multiple of 16
        float ca = 0.f, sa = 0.f;
        if (MODE == 1) {
            const int h = nbase >> 6;               // constant across lr (<64)
            ca = cosf(angles[h]);
            sa = sinf(angles[h]);
        }
        #pragma unroll
        for (int mt = 0; mt < 4; ++mt) {
            #pragma unroll
            for (int j = 0; j < 4; ++j) {
                const int m = m0 + wm * 64 + mt * 16 + lg * 4 + j;
                const int n = nbase + lr;
                const float v = acc[mt][nt][j];
                if (MODE == 0) {
                    ((float*)Cout)[(size_t)m * (TOK_ + POS_) + n] = v;
                } else if (MODE == 1) {
                    const float p = __shfl_xor(v, 1);   // partner column n^1
                    const float o = (lr & 1) ? (p * sa + v * ca)
                                             : (v * ca - p * sa);
                    const int b = m >> 11, t = m & (T_ - 1);
                    const int h = n >> 6, d = n & 63;
                    ((u16*)Cout)[(((size_t)(b * H_ + h)) * T_ + t) * D_ + d] = f2bf(o);
                } else {
                    const int b = m >> 11, t = m & (T_ - 1);
                    const int h = n >> 6, d = n & 63;
                    ((u16*)Cout)[(((size_t)(b * KVH_ + h)) * T_ + t) * D_ + d] = f2bf(v);
                }
            }
        }
    }
}

// ---------------------------------------------------------------------------
// MFMA bf16 flash attention (causal, ALiBi, "+1" denominator).
// ROUND 10 CHANGE: triangular load-balancing. Round-10 counters showed
// flash at Occupancy 13.6% / MfmaUtil 4.6% — latency+imbalance bound
// (block qt does qt+1 KV-tiles: 1:32 spread, stragglers define the tail).
// Now each block processes TWO q-tiles, bx and (T/64-1-bx): every block
// does exactly 33 tile-units; grid (T/128, B*H) = 512 blocks = 2/CU.
// Per-q-row arithmetic is IDENTICAL to the validated round-10 kernel.
// ---------------------------------------------------------------------------
__global__ __launch_bounds__(256, 3)
void flash_mfma(const u16* __restrict__ Q, const u16* __restrict__ K,
                const u16* __restrict__ V, const float* __restrict__ slopes,
                u16* __restrict__ O)
{
    __shared__ __align__(16) unsigned char lds[24576];
    unsigned char* Ks = lds;              // K tile: [key][d]  64x128B
    unsigned char* Vt = lds + 8192;       // V tile transposed: [d][key] 64x128B
    unsigned char* Ps = lds + 16384;      // P tiles: per-wave [16][64] bf16

    const int tid  = threadIdx.x;
    const int lane = tid & 63;
    const int w    = tid >> 6;
    const int lr   = lane & 15;
    const int lg   = lane >> 4;

    const int bh  = blockIdx.y;
    const int b   = bh >> 4;
    const int h   = bh & 15;
    const int kvh = h >> 2;              // GQA: h // (H/KVH)

    const float slope = expf(slopes[h]);

    const u16* Kp = K + ((size_t)(b * KVH_ + kvh)) * T_ * D_;
    const u16* Vp = V + ((size_t)(b * KVH_ + kvh)) * T_ * D_;

    unsigned char* Pw = Ps + w * 2048;   // 16 rows x 128 B, wave-private

    #pragma unroll 1
    for (int pass = 0; pass < 2; ++pass) {
        const int qt = pass ? (T_ / 64 - 1 - blockIdx.x) : blockIdx.x;
        const int q0 = qt * 64;

        const u16* Qp = Q + (((size_t)(b * H_ + h)) * T_ + q0 + w * 16) * D_;
        const bf16x8 qa0 = *reinterpret_cast<const bf16x8*>(Qp + lr * D_ + lg * 8);
        const bf16x8 qa1 = *reinterpret_cast<const bf16x8*>(Qp + lr * D_ + 32 + lg * 8);

        f32x4 acc[4] = {};
        float mrow[4], lrow[4];
        #pragma unroll
        for (int j = 0; j < 4; ++j) { mrow[j] = -INFINITY; lrow[j] = 0.f; }

        for (int jt = 0; jt <= qt; ++jt) {
            const int kv0 = jt * 64;
            __syncthreads();             // all waves done reading previous tile
            #pragma unroll
            for (int it = 0; it < 2; ++it) {
                int lin = tid + it * 256;
                int row = lin >> 3;
                int c16 = (lin & 7) * 16;
                u16x8 kv = *reinterpret_cast<const u16x8*>(
                    Kp + (size_t)(kv0 + row) * D_ + (lin & 7) * 8);
                *reinterpret_cast<u16x8*>(Ks + ((row * 128 + c16) ^ ((row & 7) << 4))) = kv;
                int key = lin & 63;
                int d8  = (lin >> 6) * 8;
                u16x8 vv = *reinterpret_cast<const u16x8*>(
                    Vp + (size_t)(kv0 + key) * D_ + d8);
                #pragma unroll
                for (int e = 0; e < 8; ++e) {
                    int d = d8 + e;
                    *reinterpret_cast<u16*>(
                        Vt + ((d * 128 + key * 2) ^ ((d & 7) << 4))) = (u16)vv[e];
                }
            }
            __syncthreads();

            f32x4 s[4];
            #pragma unroll
            for (int n = 0; n < 4; ++n) {
                int krow = n * 16 + lr;
                int swz  = (krow & 7) << 4;
                bf16x8 kb0 = *reinterpret_cast<bf16x8*>(Ks + ((krow * 128 + lg * 16) ^ swz));
                bf16x8 kb1 = *reinterpret_cast<bf16x8*>(Ks + ((krow * 128 + 64 + lg * 16) ^ swz));
                f32x4 z = {};
                z    = __builtin_amdgcn_mfma_f32_16x16x32_bf16(qa0, kb0, z, 0, 0, 0);
                s[n] = __builtin_amdgcn_mfma_f32_16x16x32_bf16(qa1, kb1, z, 0, 0, 0);
            }

            const int qbase = q0 + w * 16 + lg * 4;
            #pragma unroll
            for (int j = 0; j < 4; ++j) {
                const int qr = qbase + j;
                float a[4];
                float tmax = -INFINITY;
                #pragma unroll
                for (int n = 0; n < 4; ++n) {
                    int kg = kv0 + n * 16 + lr;
                    float vsc = s[n][j] * 0.125f + slope * (float)(qr - kg);
                    vsc = (kg <= qr) ? vsc : -INFINITY;
                    a[n] = vsc;
                    tmax = fmaxf(tmax, vsc);
                }
                #pragma unroll
                for (int off = 1; off < 16; off <<= 1)
                    tmax = fmaxf(tmax, __shfl_xor(tmax, off));
                const float mnew = fmaxf(mrow[j], tmax);
                const float sc   = __expf(mrow[j] - mnew);   // -inf -> 0 first tile
                float rsum = 0.f;
                u16 pb[4];
                #pragma unroll
                for (int n = 0; n < 4; ++n) {
                    float p = __expf(a[n] - mnew);           // masked -> 0
                    rsum += p;
                    pb[n] = f2bf(p);
                }
                #pragma unroll
                for (int off = 1; off < 16; off <<= 1)
                    rsum += __shfl_xor(rsum, off);
                lrow[j] = lrow[j] * sc + rsum;
                mrow[j] = mnew;
                #pragma unroll
                for (int dt = 0; dt < 4; ++dt) acc[dt][j] *= sc;
                const int prow = lg * 4 + j;
                #pragma unroll
                for (int n = 0; n < 4; ++n)
                    *reinterpret_cast<u16*>(
                        Pw + ((prow * 128 + (n * 16 + lr) * 2) ^ ((prow & 7) << 4))) = pb[n];
            }

            #pragma unroll
            for (int kh = 0; kh < 2; ++kh) {
                bf16x8 pa = *reinterpret_cast<bf16x8*>(
                    Pw + ((lr * 128 + kh * 64 + lg * 16) ^ ((lr & 7) << 4)));
                #pragma unroll
                for (int dt = 0; dt < 4; ++dt) {
                    int drow = dt * 16 + lr;
                    bf16x8 vb = *reinterpret_cast<bf16x8*>(
                        Vt + ((drow * 128 + kh * 64 + lg * 16) ^ ((drow & 7) << 4)));
                    acc[dt] = __builtin_amdgcn_mfma_f32_16x16x32_bf16(pa, vb, acc[dt], 0, 0, 0);
                }
            }
        }

        // epilogue: denom = 1 + l, write bf16 (B,T,H*D)
        u16* Op = O + ((size_t)b * T_ + q0 + w * 16) * (H_ * D_) + h * 64;
        #pragma unroll
        for (int j = 0; j < 4; ++j) {
            const float inv = 1.0f / (1.0f + lrow[j]);
            const int r = lg * 4 + j;
            #pragma unroll
            for (int dt = 0; dt < 4; ++dt)
                Op[(size_t)r * (H_ * D_) + dt * 16 + lr] = f2bf(acc[dt][j] * inv);
        }
    }
}

// ---------------------------------------------------------------------------
// Launcher. ws layout (u16 elems): xb 4M | Qb 4M | Kb 1M | Vb 1M | AttO 4M |
// WqT 512K | WkT 128K | WvT 128K | WoT 1M  (~31.7 MB). All regions written
// every call before read (ws is re-poisoned each timed launch).
// ---------------------------------------------------------------------------
extern "C" void kernel_launch(void* const* d_in, const int* in_sizes, int n_in,
                              void* d_out, int out_size, void* d_ws, size_t ws_size,
                              hipStream_t stream)
{
    const float* x      = (const float*)d_in[0];
    const float* Wq     = (const float*)d_in[1];
    const float* Wk     = (const float*)d_in[2];
    const float* Wv     = (const float*)d_in[3];
    const float* Wo     = (const float*)d_in[4];
    const float* ang    = (const float*)d_in[5];
    const float* slopes = (const float*)d_in[6];
    float* out = (float*)d_out;

    u16* xb   = (u16*)d_ws;
    u16* Qb   = xb   + (size_t)4096 * 1024;
    u16* Kb   = Qb   + (size_t)B_ * H_ * T_ * D_;
    u16* Vb   = Kb   + (size_t)B_ * KVH_ * T_ * D_;
    u16* AttO = Vb   + (size_t)B_ * KVH_ * T_ * D_;
    u16* WqT  = AttO + (size_t)4096 * 1024;
    u16* WkT  = WqT  + (size_t)1024 * 512;
    u16* WvT  = WkT  + (size_t)256 * 512;
    u16* WoT  = WvT  + (size_t)256 * 512;

    // Prologue: convert x, transpose+convert weights
    cvt_x<<<4096, 256, 0, stream>>>(x, xb);
    transp_k<<<dim3(1024 / 32, 512 / 32), 256, 0, stream>>>(Wq, WqT, 512, 1024);
    transp_k<<<dim3(256 / 32, 512 / 32), 256, 0, stream>>>(Wk, WkT, 512, 256);
    transp_k<<<dim3(256 / 32, 512 / 32), 256, 0, stream>>>(Wv, WvT, 512, 256);
    transp_k<<<dim3(1024 / 32, 1024 / 32), 256, 0, stream>>>(Wo, WoT, 1024, 1024);

    // Projections (bf16 MFMA)
    mfma_gemm<1><<<dim3(8, 32), 256, 0, stream>>>(xb, 1024, 512, WqT, 512, Qb, ang);
    mfma_gemm<2><<<dim3(2, 32), 256, 0, stream>>>(xb, 1024, 512, WkT, 512, Kb, nullptr);
    mfma_gemm<2><<<dim3(2, 32), 256, 0, stream>>>(xb, 1024, 0,   WvT, 512, Vb, nullptr);

    // Flash attention (balanced: 2 q-tiles/block) -> AttO bf16 (B,T,H*D)
    flash_mfma<<<dim3(T_ / 128, B_ * H_), 256, 0, stream>>>(Qb, Kb, Vb, slopes, AttO);

    // out = AttO @ Wo (bf16 MFMA, fp32 out)
    mfma_gemm<0><<<dim3(8, 32), 256, 0, stream>>>(AttO, 1024, 0, WoT, 1024, out, nullptr);
}